// Round 3
// baseline (913.817 us; speedup 1.0000x reference)
//
#include <hip/hip_runtime.h>

typedef short s16x8 __attribute__((ext_vector_type(8)));
typedef float f32x16 __attribute__((ext_vector_type(16)));
typedef float f32x4 __attribute__((ext_vector_type(4)));

__device__ __forceinline__ float bf2f(short s) {
  unsigned int u = ((unsigned int)(unsigned short)s) << 16;
  return __builtin_bit_cast(float, u);
}
__device__ __forceinline__ short f2bf(float f) {
  unsigned int u = __builtin_bit_cast(unsigned int, f);
  u += 0x7fffu + ((u >> 16) & 1u);   // RNE
  return (short)(u >> 16);
}

#define GEPS 1e-20f

// ---------------- codebook prep ----------------
// CBI: GEMM1 B (n=v,k=d), hi/lo interleaved per (tile,step):
//   addr = (T*64+S)*1024 + p*512 + hl*256 + (v&31)*8 + (d&7);  T=v>>5,S=d>>4,p=(d>>3)&1
// CTX: GEMM2 B (n=d,k=v), hi only:
//   addr = (T*64+S)*512 + p*256 + (d&31)*8 + (v&7);            T=d>>5,S=v>>4,p=(v>>3)&1
__global__ __launch_bounds__(256) void k_prep(const float* __restrict__ cb,
                                              short* __restrict__ CBI,
                                              short* __restrict__ CTX) {
  const int idx = blockIdx.x * 256 + threadIdx.x;   // 131072 threads
  {
    const int v = idx >> 7, dg = idx & 127;          // covers d = dg*8 .. +8
    const float* p = cb + v * 1024 + dg * 8;
    f32x4 x0 = *(const f32x4*)p;
    f32x4 x1 = *(const f32x4*)(p + 4);
    s16x8 hi, lo;
#pragma unroll
    for (int j = 0; j < 8; ++j) {
      float val = (j < 4) ? x0[j] : x1[j - 4];
      hi[j] = f2bf(val);
      lo[j] = f2bf(val - bf2f(hi[j]));
    }
    const int base = ((v >> 5) * 64 + (dg >> 1)) * 1024 + (dg & 1) * 512 + (v & 31) * 8;
    *(s16x8*)(CBI + base) = hi;
    *(s16x8*)(CBI + base + 256) = lo;
  }
  {
    const int d = idx >> 7, vg = idx & 127;          // covers v = vg*8 .. +8
    s16x8 hi;
#pragma unroll
    for (int j = 0; j < 8; ++j) hi[j] = f2bf(cb[(vg * 8 + j) * 1024 + d]);
    const int base = ((d >> 5) * 64 + (vg >> 1)) * 512 + (vg & 1) * 256 + (d & 31) * 8;
    *(s16x8*)(CTX + base) = hi;
  }
}

// ---------------- fused GVQ ----------------
// Block: 1024 thr = 16 waves (wm 0..1 x wn 0..7). M=64 rows/block, grid 512.
// Wave (wm,wn): rows [32wm,32wm+32), cols [128wn,128wn+128) as 4x 32x32 tiles.

__device__ __forceinline__ void stage_load(const float* __restrict__ src, int k0,
                                           int tid, f32x4* pf) {
#pragma unroll
  for (int i = 0; i < 2; ++i) {
    const int c = tid + i * 1024, m = c >> 5, g = c & 31;
    const float* p = src + m * 1024 + k0 + g * 8;
    pf[i * 2]     = *(const f32x4*)p;
    pf[i * 2 + 1] = *(const f32x4*)(p + 4);
  }
}

template <bool LO>
__device__ __forceinline__ void conv_store(const f32x4* pf, short* __restrict__ Ahb,
                                           short* __restrict__ Alb, int tid) {
#pragma unroll
  for (int i = 0; i < 2; ++i) {
    const int c = tid + i * 1024, m = c >> 5, g = c & 31;
    s16x8 hi, lo;
#pragma unroll
    for (int j = 0; j < 8; ++j) {
      float v = pf[i * 2 + (j >> 2)][j & 3];
      hi[j] = f2bf(v);
      if (LO) lo[j] = f2bf(v - bf2f(hi[j]));
    }
    const int off = m * 256 + ((g ^ (m & 15)) << 3);
    *(s16x8*)(Ahb + off) = hi;
    if (LO) *(s16x8*)(Alb + off) = lo;
  }
}

__device__ __forceinline__ void gemm1_q(const short* __restrict__ Ahb,
                                        const short* __restrict__ Alb,
                                        const short* __restrict__ CBI,
                                        int wn, int wm, int ln, int h, int kq,
                                        f32x16* acc) {
  const int arow = wm * 32 + ln;
  const short* ap = Ahb + arow * 256;
  const short* al = Alb + arow * 256;
  const int sw = arow & 15;
  for (int s = 0; s < 16; ++s) {
    const int S = kq * 16 + s;
    const int ao = ((2 * s + h) ^ sw) << 3;
    s16x8 a  = *(const s16x8*)(ap + ao);
    s16x8 av = *(const s16x8*)(al + ao);
#pragma unroll
    for (int nt = 0; nt < 4; ++nt) {
      const short* bb = CBI + (((wn * 4 + nt) * 64 + S) << 10) + h * 512 + ln * 8;
      s16x8 bh = *(const s16x8*)bb;
      s16x8 bl = *(const s16x8*)(bb + 256);
      acc[nt] = __builtin_amdgcn_mfma_f32_32x32x16_bf16(a,  bh, acc[nt], 0, 0, 0);
      acc[nt] = __builtin_amdgcn_mfma_f32_32x32x16_bf16(av, bh, acc[nt], 0, 0, 0);
      acc[nt] = __builtin_amdgcn_mfma_f32_32x32x16_bf16(a,  bl, acc[nt], 0, 0, 0);
    }
  }
}

__device__ __forceinline__ void gemm2_q(const short* __restrict__ Ahb,
                                        const short* __restrict__ CTX,
                                        int wn, int wm, int ln, int h, int vq,
                                        f32x16* acc) {
  const int arow = wm * 32 + ln;
  const short* ap = Ahb + arow * 256;
  const int sw = arow & 15;
  for (int s = 0; s < 16; ++s) {
    const int S = vq * 16 + s;
    const int ao = ((2 * s + h) ^ sw) << 3;
    s16x8 a = *(const s16x8*)(ap + ao);
#pragma unroll
    for (int nt = 0; nt < 4; ++nt) {
      const short* bb = CTX + (((wn * 4 + nt) * 64 + S) << 9) + h * 256 + ln * 8;
      s16x8 b = *(const s16x8*)bb;
      acc[nt] = __builtin_amdgcn_mfma_f32_32x32x16_bf16(a, b, acc[nt], 0, 0, 0);
    }
  }
}

__global__ __launch_bounds__(1024) void k_gvq(
    const float* __restrict__ X,
    const short* __restrict__ CBI,
    const short* __restrict__ CTX,
    const float* __restrict__ G,
    float* __restrict__ outQ,
    float* __restrict__ outP) {
  __shared__ short Ah[2][16384];
  __shared__ short Al[2][16384];
  __shared__ float redL[16][32];
  __shared__ float rowMax[64];
  __shared__ float rowInv[64];

  const int tid = threadIdx.x;
  const int l = tid & 63, w = tid >> 6;
  const int ln = l & 31, h = l >> 5;
  const int wm = w >> 3, wn = w & 7;
  const int r0 = blockIdx.x * 64;
  const float* Xr = X + r0 * 1024;

  f32x4 pf[4];
  f32x16 acc[4];
#pragma unroll
  for (int nt = 0; nt < 4; ++nt)
#pragma unroll
    for (int i = 0; i < 16; ++i) acc[nt][i] = 0.0f;

  // ---- GEMM1: quarter-pipelined X staging, 3-term bf16 split ----
  stage_load(Xr, 0, tid, pf);
  conv_store<true>(pf, Ah[0], Al[0], tid);
  __syncthreads();
  for (int kq = 0; kq < 4; ++kq) {
    if (kq < 3) stage_load(Xr, (kq + 1) * 256, tid, pf);
    gemm1_q(Ah[kq & 1], Al[kq & 1], CBI, wn, wm, ln, h, kq, acc);
    if (kq < 3) conv_store<true>(pf, Ah[(kq + 1) & 1], Al[(kq + 1) & 1], tid);
    __syncthreads();
  }

  // ---- gumbel + /T; per-row max ----
  float pmax[16];
#pragma unroll
  for (int r = 0; r < 16; ++r) pmax[r] = -3.0e38f;
#pragma unroll
  for (int nt = 0; nt < 4; ++nt) {
    const int c = wn * 128 + nt * 32 + ln;
    const float* gp = G + (r0 + wm * 32) * 1024 + c;
#pragma unroll
    for (int r = 0; r < 16; ++r) {
      const int rho = (r & 3) + 8 * (r >> 2) + 4 * h;
      float u = gp[rho * 1024];
      float gv = -__logf(-__logf(u + GEPS) + GEPS);
      float y = (acc[nt][r] + gv) * 2.0f;
      acc[nt][r] = y;
      pmax[r] = fmaxf(pmax[r], y);
    }
  }
#pragma unroll
  for (int off = 16; off; off >>= 1)
#pragma unroll
    for (int r = 0; r < 16; ++r)
      pmax[r] = fmaxf(pmax[r], __shfl_xor(pmax[r], off, 64));
  if (ln == 0) {
#pragma unroll
    for (int r = 0; r < 16; ++r)
      redL[w][(r & 3) + 8 * (r >> 2) + 4 * h] = pmax[r];
  }
  __syncthreads();
  if (tid < 64) {
    const int wmr = tid >> 5, lr = tid & 31;
    float m = redL[wmr * 8][lr];
#pragma unroll
    for (int j = 1; j < 8; ++j) m = fmaxf(m, redL[wmr * 8 + j][lr]);
    rowMax[tid] = m;
  }
  __syncthreads();

  // ---- exp + per-row sum ----
  float psum[16];
#pragma unroll
  for (int r = 0; r < 16; ++r) psum[r] = 0.0f;
#pragma unroll
  for (int nt = 0; nt < 4; ++nt) {
#pragma unroll
    for (int r = 0; r < 16; ++r) {
      const int rho = wm * 32 + (r & 3) + 8 * (r >> 2) + 4 * h;
      float e = __expf(acc[nt][r] - rowMax[rho]);
      acc[nt][r] = e;
      psum[r] += e;
    }
  }
#pragma unroll
  for (int off = 16; off; off >>= 1)
#pragma unroll
    for (int r = 0; r < 16; ++r)
      psum[r] += __shfl_xor(psum[r], off, 64);
  if (ln == 0) {
#pragma unroll
    for (int r = 0; r < 16; ++r)
      redL[w][(r & 3) + 8 * (r >> 2) + 4 * h] = psum[r];
  }
  __syncthreads();
  if (tid < 64) {
    const int wmr = tid >> 5, lr = tid & 31;
    float s = redL[wmr * 8][lr];
#pragma unroll
    for (int j = 1; j < 8; ++j) s += redL[wmr * 8 + j][lr];
    rowInv[tid] = 1.0f / s;
  }
  __syncthreads();

  // ---- P stores (fp32 output; also the GEMM2 A source) ----
#pragma unroll
  for (int nt = 0; nt < 4; ++nt) {
    const int c = wn * 128 + nt * 32 + ln;
#pragma unroll
    for (int r = 0; r < 16; ++r) {
      const int rho = wm * 32 + (r & 3) + 8 * (r >> 2) + 4 * h;
      float p = acc[nt][r] * rowInv[rho];
      outP[(r0 + rho) * 1024 + c] = p;
    }
  }
  __syncthreads();   // P visible block-wide (same CU)

  // ---- GEMM2: quarter-pipelined P staging (L2-hot readback), Q = P @ CB ----
#pragma unroll
  for (int nt = 0; nt < 4; ++nt)
#pragma unroll
    for (int i = 0; i < 16; ++i) acc[nt][i] = 0.0f;
  const float* Pr = outP + r0 * 1024;
  stage_load(Pr, 0, tid, pf);
  conv_store<false>(pf, Ah[0], nullptr, tid);
  __syncthreads();
  for (int vq = 0; vq < 4; ++vq) {
    if (vq < 3) stage_load(Pr, (vq + 1) * 256, tid, pf);
    gemm2_q(Ah[vq & 1], CTX, wn, wm, ln, h, vq, acc);
    if (vq < 3) conv_store<false>(pf, Ah[(vq + 1) & 1], nullptr, tid);
    __syncthreads();
  }

  // ---- Q stores ----
#pragma unroll
  for (int nt = 0; nt < 4; ++nt) {
    const int c = wn * 128 + nt * 32 + ln;
#pragma unroll
    for (int r = 0; r < 16; ++r) {
      const int rho = wm * 32 + (r & 3) + 8 * (r >> 2) + 4 * h;
      outQ[(r0 + rho) * 1024 + c] = acc[nt][r];
    }
  }
}

extern "C" void kernel_launch(void* const* d_in, const int* in_sizes, int n_in,
                              void* d_out, int out_size, void* d_ws, size_t ws_size,
                              hipStream_t stream) {
  const float* X  = (const float*)d_in[0];   // (8,4096,1024) fp32
  const float* CB = (const float*)d_in[1];   // (1024,1024) fp32
  const float* G  = (const float*)d_in[2];   // (8,4096,1024) fp32
  float* outQ = (float*)d_out;               // quantized (32M floats)
  float* outP = outQ + 33554432;             // soft_one_hot (32M floats)
  short* CBI = (short*)d_ws;                 // 4 MB
  short* CTX = CBI + 2097152;                // 2 MB

  k_prep<<<512, 256, 0, stream>>>(CB, CBI, CTX);
  k_gvq<<<512, 1024, 0, stream>>>(X, CBI, CTX, G, outQ, outP);
}